// Round 8
// baseline (136.334 us; speedup 1.0000x reference)
//
#include <hip/hip_runtime.h>

#define NPIX 16384   // 128*128
#define NN   256     // max_nodes
#define CC   256     // NFEAT
#define HH   128     // SCORER_HIDDEN
#define EE   65280   // NN*(NN-1)
#define BB   4
#define NG   8       // histogram privatization groups

// ---------------- Kernel 1: sigmoid + exact top-k via register radix select ----------------
__global__ __launch_bounds__(1024) void k_topk(
    const float* __restrict__ jl, const float* __restrict__ off,
    int* __restrict__ topi, int* __restrict__ valid, float* __restrict__ inv_deg,
    float* __restrict__ out_nodes, float* __restrict__ Sbuf)
{
  __shared__ int hist[NG][257];
  __shared__ int histT[256];
  __shared__ unsigned long long s_sel[NN];
  __shared__ unsigned long long s_T;
  __shared__ int s_digit, s_krem, s_cnt, s_vcnt, s_break;

  const int b = blockIdx.x;
  const int tid = threadIdx.x;
  const int grp = (tid >> 7) & (NG - 1);
  if (tid == 0) { s_cnt = 0; s_vcnt = 0; }

  // zero the 4 colsum buffers for this image (layout: Sbuf[l*BB*CC + b*CC + c])
  {
    int l = tid >> 8, c = tid & 255;
    Sbuf[l*BB*CC + b*CC + c] = 0.0f;
  }

  unsigned long long rk[16];
  const float* p = jl + (size_t)b * NPIX;
  #pragma unroll
  for (int r = 0; r < 16; ++r) {
    int i = tid + (r << 10);
    float x = p[i];
    float pr = 1.0f / (1.0f + expf(-x));
    unsigned bits = __float_as_uint(pr);
    rk[r] = ((unsigned long long)bits << 32) | (unsigned)(0xFFFFFFFFu - (unsigned)i);
  }

  unsigned long long prefix = 0;
  int k = NN;
  int shift = 56;
  int brk = 0;
  for (int pass = 0; pass < 8 && !brk; ++pass) {
    shift = 56 - 8 * pass;
    for (int i = tid; i < NG * 257; i += 1024) ((int*)hist)[i] = 0;
    __syncthreads();
    unsigned long long pmask = (pass == 0) ? 0ULL : (~0ULL << (shift + 8));
    #pragma unroll
    for (int r = 0; r < 16; ++r) {
      unsigned long long kk = rk[r];
      if ((kk & pmask) == prefix)
        atomicAdd(&hist[grp][(int)((kk >> shift) & 255)], 1);
    }
    __syncthreads();
    if (tid < 256) {
      int t = 0;
      #pragma unroll
      for (int g = 0; g < NG; ++g) t += hist[g][tid];
      histT[tid] = t;
    }
    __syncthreads();
    if (tid < 64) {
      int h0 = histT[4*tid + 0], h1 = histT[4*tid + 1];
      int h2 = histT[4*tid + 2], h3 = histT[4*tid + 3];
      int tot = h0 + h1 + h2 + h3;
      int suf = tot;
      #pragma unroll
      for (int d = 1; d < 64; d <<= 1) {
        int o = __shfl_down(suf, d);
        if (tid + d < 64) suf += o;
      }
      int above = suf - tot;
      int c3 = h3 + above;
      int c2 = c3 + h2;
      int c1 = c2 + h1;
      int c0 = c1 + h0;
      if      (c3 >= k && above < k) { s_digit = 4*tid+3; s_krem = k - above; s_break = (h3 == 1); }
      else if (c2 >= k && c3    < k) { s_digit = 4*tid+2; s_krem = k - c3;    s_break = (h2 == 1); }
      else if (c1 >= k && c2    < k) { s_digit = 4*tid+1; s_krem = k - c2;    s_break = (h1 == 1); }
      else if (c0 >= k && c1    < k) { s_digit = 4*tid+0; s_krem = k - c1;    s_break = (h0 == 1); }
    }
    __syncthreads();
    prefix |= ((unsigned long long)s_digit) << shift;
    k = s_krem;
    brk = s_break;
  }

  if (shift == 0) {
    if (tid == 0) s_T = prefix;
  } else {
    unsigned long long known_mask = ~0ULL << shift;
    #pragma unroll
    for (int r = 0; r < 16; ++r)
      if ((rk[r] & known_mask) == prefix) s_T = rk[r];
  }
  __syncthreads();
  unsigned long long T = s_T;

  #pragma unroll
  for (int r = 0; r < 16; ++r) {
    unsigned long long kk = rk[r];
    if (kk >= T) { int pos = atomicAdd(&s_cnt, 1); s_sel[pos] = kk; }
  }
  __syncthreads();

  int my_rank = -1, my_v = 0;
  if (tid < NN) {
    unsigned long long mine = s_sel[tid];
    int rank = 0;
    #pragma unroll 16
    for (int j = 0; j < NN; ++j) rank += (s_sel[j] > mine) ? 1 : 0;
    unsigned bits = (unsigned)(mine >> 32);
    int v = bits > 0x3F000000u ? 1 : 0;
    int idx = (int)(0xFFFFFFFFu - (unsigned)(mine & 0xFFFFFFFFull));
    if (v) atomicAdd(&s_vcnt, 1);
    topi[b*NN + rank] = idx;
    valid[b*NN + rank] = v;
    int iy = idx >> 7;
    int ix = idx & 127;
    float yo = off[((size_t)b*2 + 0) * NPIX + idx];
    float xo = off[((size_t)b*2 + 1) * NPIX + idx];
    out_nodes[(b*NN + rank)*2 + 0] = ((float)ix + 0.5f + xo) * 4.0f;
    out_nodes[(b*NN + rank)*2 + 1] = ((float)iy + 0.5f + yo) * 4.0f;
    my_rank = rank; my_v = v;
  }
  __syncthreads();
  if (tid < NN) {
    int V = s_vcnt;
    inv_deg[b*NN + my_rank] = (my_v && V >= 2) ? 1.0f / (float)(V - 1) : 0.0f;
  }
}

// ---------------- Kernel 2: gather node features + fused colsum into S0 ----------------
__global__ __launch_bounds__(256) void k_gather(
    const float* __restrict__ nmap, const int* __restrict__ topi,
    const int* __restrict__ valid, float* __restrict__ x, float* __restrict__ S0)
{
  const int bn = blockIdx.x;
  const int b = bn >> 8;
  const int c = threadIdx.x;
  int pix = topi[bn];
  int v = valid[bn];
  float val = v ? nmap[(((size_t)b*CC + c) << 14) + pix] : 0.0f;
  x[(size_t)bn*CC + c] = val;
  if (val != 0.0f) atomicAdd(&S0[b*CC + c], val);
}

// ---------------- Kernel 3: GNN layer, LDS-free main loop, P2 fused as S-row ----------------
// out[r][col] = relu(A1 + inv_r*(P2[col] - A2) + bias) * valid
// A1 = x@Wself, A2 = x@Wnbr, P2 = S@Wnbr (S treated as 9th accumulator stream).
// Block: 4 rows x 256 cols x K-split 2 = 512 threads. Grid BB*64 = 256.
// All vector components accessed EXPLICITLY (.x/.y/.z/.w) -- no runtime-indexed
// vector reads (those allocate scratch, skill rule #20).
__global__ __launch_bounds__(512) void k_gnn(
    const float* __restrict__ x, const float* __restrict__ S,
    const float* __restrict__ inv_deg, const int* __restrict__ valid,
    const float* __restrict__ Wself, const float* __restrict__ Wnbr,
    const float* __restrict__ bias, float* __restrict__ xout,
    float* __restrict__ Snext,     // may be null
    float* __restrict__ out_emb)   // may be null
{
  __shared__ float red[9][256];    // 9 KiB, kw=1 partials (A1x4, A2x4, P2)
  const int b   = blockIdx.x >> 6;
  const int n0  = (blockIdx.x & 63) * 4;
  const int tid = threadIdx.x;
  const int col = tid & 255;
  const int kw  = tid >> 8;        // 0/1, 128 c's each

  const float4* x4 = (const float4*)(x + ((size_t)(b*NN + n0))*CC);
  const float4* S4 = (const float4*)(S + (size_t)b*CC);
  float a10=0,a11=0,a12=0,a13=0;   // A1 rows 0..3
  float a20=0,a21=0,a22=0,a23=0;   // A2 rows 0..3
  float a2S=0;                     // P2 partial
  const int q0 = kw << 5;
  #pragma unroll 2
  for (int c4 = 0; c4 < 32; ++c4) {
    int q = q0 + c4;
    float4 xv0 = x4[q];
    float4 xv1 = x4[64 + q];
    float4 xv2 = x4[128 + q];
    float4 xv3 = x4[192 + q];
    float4 sv  = S4[q];
    int cb = q << 2;
    {
      float w1 = Wself[(size_t)(cb+0)*CC + col];
      float w2 = Wnbr [(size_t)(cb+0)*CC + col];
      a10 += xv0.x*w1; a11 += xv1.x*w1; a12 += xv2.x*w1; a13 += xv3.x*w1;
      a20 += xv0.x*w2; a21 += xv1.x*w2; a22 += xv2.x*w2; a23 += xv3.x*w2;
      a2S += sv.x*w2;
    }
    {
      float w1 = Wself[(size_t)(cb+1)*CC + col];
      float w2 = Wnbr [(size_t)(cb+1)*CC + col];
      a10 += xv0.y*w1; a11 += xv1.y*w1; a12 += xv2.y*w1; a13 += xv3.y*w1;
      a20 += xv0.y*w2; a21 += xv1.y*w2; a22 += xv2.y*w2; a23 += xv3.y*w2;
      a2S += sv.y*w2;
    }
    {
      float w1 = Wself[(size_t)(cb+2)*CC + col];
      float w2 = Wnbr [(size_t)(cb+2)*CC + col];
      a10 += xv0.z*w1; a11 += xv1.z*w1; a12 += xv2.z*w1; a13 += xv3.z*w1;
      a20 += xv0.z*w2; a21 += xv1.z*w2; a22 += xv2.z*w2; a23 += xv3.z*w2;
      a2S += sv.z*w2;
    }
    {
      float w1 = Wself[(size_t)(cb+3)*CC + col];
      float w2 = Wnbr [(size_t)(cb+3)*CC + col];
      a10 += xv0.w*w1; a11 += xv1.w*w1; a12 += xv2.w*w1; a13 += xv3.w*w1;
      a20 += xv0.w*w2; a21 += xv1.w*w2; a22 += xv2.w*w2; a23 += xv3.w*w2;
      a2S += sv.w*w2;
    }
  }

  if (kw == 1) {
    red[0][col]=a10; red[1][col]=a11; red[2][col]=a12; red[3][col]=a13;
    red[4][col]=a20; red[5][col]=a21; red[6][col]=a22; red[7][col]=a23;
    red[8][col]=a2S;
  }
  __syncthreads();
  if (kw == 0) {
    float pv = a2S + red[8][col];
    float bv = bias[col];
    float A1[4] = {a10+red[0][col], a11+red[1][col], a12+red[2][col], a13+red[3][col]};
    float A2[4] = {a20+red[4][col], a21+red[5][col], a22+red[6][col], a23+red[7][col]};
    float cs = 0.f;
    #pragma unroll
    for (int r = 0; r < 4; ++r) {
      float inv = inv_deg[b*NN + n0 + r];
      float o = fmaxf(A1[r] + inv*(pv - A2[r]) + bv, 0.f);
      o = valid[b*NN + n0 + r] ? o : 0.f;
      size_t oi = ((size_t)(b*NN + n0 + r))*CC + col;
      xout[oi] = o;
      if (out_emb) out_emb[oi] = o;
      cs += o;
    }
    if (Snext && cs != 0.f) atomicAdd(&Snext[b*CC + col], cs);
  }
}

// ---------------- Kernel 4: u = x@Ws1[:C], v_t = (x@Ws1[C:])^T ----------------
// Explicit component access; block 4 rows x 128 h x K-split 4 = 512 thr; grid 256.
__global__ __launch_bounds__(512) void k_uv(
    const float* __restrict__ x, const float* __restrict__ Ws1,
    float* __restrict__ u, float* __restrict__ vt)
{
  __shared__ float red[3][8][128];   // 12 KiB
  const int b   = blockIdx.x >> 6;
  const int n0  = (blockIdx.x & 63) * 4;
  const int tid = threadIdx.x;
  const int h   = tid & 127;
  const int kw  = tid >> 7;          // 0..3, 64 c's each

  const float4* x4 = (const float4*)(x + ((size_t)(b*NN + n0))*CC);
  float au0=0,au1=0,au2=0,au3=0, av0=0,av1=0,av2=0,av3=0;
  #pragma unroll 2
  for (int c4 = 0; c4 < 16; ++c4) {
    int q = kw*16 + c4;
    float4 xv0 = x4[q];
    float4 xv1 = x4[64 + q];
    float4 xv2 = x4[128 + q];
    float4 xv3 = x4[192 + q];
    int cb = q << 2;
    {
      float w1 = Ws1[(size_t)(cb+0)*HH + h];
      float w2 = Ws1[(size_t)(256+cb+0)*HH + h];
      au0 += xv0.x*w1; av0 += xv0.x*w2;
      au1 += xv1.x*w1; av1 += xv1.x*w2;
      au2 += xv2.x*w1; av2 += xv2.x*w2;
      au3 += xv3.x*w1; av3 += xv3.x*w2;
    }
    {
      float w1 = Ws1[(size_t)(cb+1)*HH + h];
      float w2 = Ws1[(size_t)(256+cb+1)*HH + h];
      au0 += xv0.y*w1; av0 += xv0.y*w2;
      au1 += xv1.y*w1; av1 += xv1.y*w2;
      au2 += xv2.y*w1; av2 += xv2.y*w2;
      au3 += xv3.y*w1; av3 += xv3.y*w2;
    }
    {
      float w1 = Ws1[(size_t)(cb+2)*HH + h];
      float w2 = Ws1[(size_t)(256+cb+2)*HH + h];
      au0 += xv0.z*w1; av0 += xv0.z*w2;
      au1 += xv1.z*w1; av1 += xv1.z*w2;
      au2 += xv2.z*w1; av2 += xv2.z*w2;
      au3 += xv3.z*w1; av3 += xv3.z*w2;
    }
    {
      float w1 = Ws1[(size_t)(cb+3)*HH + h];
      float w2 = Ws1[(size_t)(256+cb+3)*HH + h];
      au0 += xv0.w*w1; av0 += xv0.w*w2;
      au1 += xv1.w*w1; av1 += xv1.w*w2;
      au2 += xv2.w*w1; av2 += xv2.w*w2;
      au3 += xv3.w*w1; av3 += xv3.w*w2;
    }
  }
  if (kw > 0) {
    red[kw-1][0][h]=au0; red[kw-1][1][h]=au1; red[kw-1][2][h]=au2; red[kw-1][3][h]=au3;
    red[kw-1][4][h]=av0; red[kw-1][5][h]=av1; red[kw-1][6][h]=av2; red[kw-1][7][h]=av3;
  }
  __syncthreads();
  if (kw == 0) {
    float AU[4] = {au0,au1,au2,au3};
    float AV[4] = {av0,av1,av2,av3};
    #pragma unroll
    for (int g = 0; g < 3; ++g) {
      AU[0] += red[g][0][h]; AU[1] += red[g][1][h];
      AU[2] += red[g][2][h]; AU[3] += red[g][3][h];
      AV[0] += red[g][4][h]; AV[1] += red[g][5][h];
      AV[2] += red[g][6][h]; AV[3] += red[g][7][h];
    }
    #pragma unroll
    for (int r = 0; r < 4; ++r) {
      u [((size_t)(b*NN + n0 + r))*HH + h] = AU[r];
      vt[((size_t)b*HH + h)*NN + (n0 + r)] = AV[r];
    }
  }
}

// ---------------- Kernel 5: per-edge scorer, LDS-free ----------------
__global__ __launch_bounds__(256) void k_edges(
    const float* __restrict__ u, const float* __restrict__ vt,
    const float* __restrict__ bs1, const float* __restrict__ Ws2,
    const float* __restrict__ bs2, const int* __restrict__ valid,
    float* __restrict__ out_logits, float* __restrict__ out_keep)
{
  const int b = blockIdx.x >> 8;
  const int i = blockIdx.x & 255;   // src node
  const int j = threadIdx.x;        // dst node
  const float4* u4  = (const float4*)(u + ((size_t)(b*NN + i))*HH);
  const float4* b14 = (const float4*)bs1;
  const float4* w24 = (const float4*)Ws2;
  const float* vrow = vt + (size_t)b*HH*NN;
  float acc = 0.f;
  #pragma unroll 4
  for (int h4 = 0; h4 < 32; ++h4) {
    float4 uu = u4[h4];
    float4 bb = b14[h4];
    float4 ww = w24[h4];
    int hb = h4 << 2;
    float t0 = uu.x + bb.x + vrow[(size_t)(hb+0)*NN + j];
    float t1 = uu.y + bb.y + vrow[(size_t)(hb+1)*NN + j];
    float t2 = uu.z + bb.z + vrow[(size_t)(hb+2)*NN + j];
    float t3 = uu.w + bb.w + vrow[(size_t)(hb+3)*NN + j];
    acc += fmaxf(t0, 0.f)*ww.x + fmaxf(t1, 0.f)*ww.y
         + fmaxf(t2, 0.f)*ww.z + fmaxf(t3, 0.f)*ww.w;
  }
  acc += bs2[0];
  if (j != i) {
    int e = i*255 + (j < i ? j : j - 1);
    int ev = valid[b*NN + i] & valid[b*NN + j];
    out_logits[(size_t)b*EE + e] = acc;
    out_keep  [(size_t)b*EE + e] = (acc > 0.f && ev) ? 1.0f : 0.0f;
  }
}

extern "C" void kernel_launch(void* const* d_in, const int* in_sizes, int n_in,
                              void* d_out, int out_size, void* d_ws, size_t ws_size,
                              hipStream_t stream) {
  const float* jl    = (const float*)d_in[0];
  const float* off   = (const float*)d_in[1];
  const float* nmap  = (const float*)d_in[2];
  const float* Wself = (const float*)d_in[3];
  const float* Wnbr  = (const float*)d_in[4];
  const float* bg    = (const float*)d_in[5];
  const float* Ws1   = (const float*)d_in[6];
  const float* bs1   = (const float*)d_in[7];
  const float* Ws2   = (const float*)d_in[8];
  const float* bs2   = (const float*)d_in[9];

  char* ws = (char*)d_ws;
  int*   topi    = (int*)  (ws + 0);                 //  4 KiB
  int*   valid   = (int*)  (ws + 4096);              //  4 KiB
  float* inv_deg = (float*)(ws + 8192);              //  4 KiB
  float* Sbuf    = (float*)(ws + 12288);             // 16 KiB (layer colsums)
  float* xa      = (float*)(ws + 28672);             //  1 MiB
  float* xb      = (float*)(ws + 28672 + 1048576);   //  1 MiB
  float* u       = (float*)(ws + 2125824);           //  512 KiB
  float* vt      = (float*)(ws + 2650112);           //  512 KiB

  float* out        = (float*)d_out;
  float* out_nodes  = out;                  // [4,256,2]   -> 2048
  float* out_emb    = out + 2048;           // [4,256,256] -> 262144
  float* out_logits = out + 264192;         // [4,65280]   -> 261120
  float* out_keep   = out + 525312;         // [4,65280]   -> 261120

  hipLaunchKernelGGL(k_topk,   dim3(BB),     dim3(1024), 0, stream,
                     jl, off, topi, valid, inv_deg, out_nodes, Sbuf);
  hipLaunchKernelGGL(k_gather, dim3(BB*NN),  dim3(256),  0, stream,
                     nmap, topi, valid, xa, Sbuf);

  float* xc = xa; float* xn = xb;
  for (int l = 0; l < 3; ++l) {
    hipLaunchKernelGGL(k_gnn, dim3(256), dim3(512), 0, stream,
                       xc, Sbuf + l*BB*CC, inv_deg, valid,
                       Wself + (size_t)l*CC*CC, Wnbr + (size_t)l*CC*CC, bg + l*CC,
                       xn,
                       (l < 2) ? (Sbuf + (l+1)*BB*CC) : (float*)nullptr,
                       (l == 2) ? out_emb : (float*)nullptr);
    float* t = xc; xc = xn; xn = t;
  }

  hipLaunchKernelGGL(k_uv,    dim3(256),   dim3(512), 0, stream, xc, Ws1, u, vt);
  hipLaunchKernelGGL(k_edges, dim3(BB*NN), dim3(256), 0, stream,
                     u, vt, bs1, Ws2, bs2, valid, out_logits, out_keep);
}

// Round 9
// 120.304 us; speedup vs baseline: 1.1332x; 1.1332x over previous
//
#include <hip/hip_runtime.h>

#define NPIX 16384   // 128*128
#define NN   256     // max_nodes
#define CC   256     // NFEAT
#define HH   128     // SCORER_HIDDEN
#define EE   65280   // NN*(NN-1)
#define BB   4
#define NG   8       // histogram privatization groups

// ---------------- Kernel 1: sigmoid + exact top-k via register radix select ----------------
__global__ __launch_bounds__(1024) void k_topk(
    const float* __restrict__ jl, const float* __restrict__ off,
    int* __restrict__ topi, int* __restrict__ valid, float* __restrict__ inv_deg,
    float* __restrict__ out_nodes, float* __restrict__ Sbuf)
{
  __shared__ int hist[NG][257];
  __shared__ int histT[256];
  __shared__ unsigned long long s_sel[NN];
  __shared__ unsigned long long s_T;
  __shared__ int s_digit, s_krem, s_cnt, s_vcnt, s_break;

  const int b = blockIdx.x;
  const int tid = threadIdx.x;
  const int grp = (tid >> 7) & (NG - 1);
  if (tid == 0) { s_cnt = 0; s_vcnt = 0; }

  // zero the 4 colsum buffers for this image (layout: Sbuf[l*BB*CC + b*CC + c])
  {
    int l = tid >> 8, c = tid & 255;
    Sbuf[l*BB*CC + b*CC + c] = 0.0f;
  }

  unsigned long long rk[16];
  const float* p = jl + (size_t)b * NPIX;
  #pragma unroll
  for (int r = 0; r < 16; ++r) {
    int i = tid + (r << 10);
    float x = p[i];
    float pr = 1.0f / (1.0f + expf(-x));
    unsigned bits = __float_as_uint(pr);
    rk[r] = ((unsigned long long)bits << 32) | (unsigned)(0xFFFFFFFFu - (unsigned)i);
  }

  unsigned long long prefix = 0;
  int k = NN;
  int shift = 56;
  int brk = 0;
  for (int pass = 0; pass < 8 && !brk; ++pass) {
    shift = 56 - 8 * pass;
    for (int i = tid; i < NG * 257; i += 1024) ((int*)hist)[i] = 0;
    __syncthreads();
    unsigned long long pmask = (pass == 0) ? 0ULL : (~0ULL << (shift + 8));
    #pragma unroll
    for (int r = 0; r < 16; ++r) {
      unsigned long long kk = rk[r];
      if ((kk & pmask) == prefix)
        atomicAdd(&hist[grp][(int)((kk >> shift) & 255)], 1);
    }
    __syncthreads();
    if (tid < 256) {
      int t = 0;
      #pragma unroll
      for (int g = 0; g < NG; ++g) t += hist[g][tid];
      histT[tid] = t;
    }
    __syncthreads();
    if (tid < 64) {
      int h0 = histT[4*tid + 0], h1 = histT[4*tid + 1];
      int h2 = histT[4*tid + 2], h3 = histT[4*tid + 3];
      int tot = h0 + h1 + h2 + h3;
      int suf = tot;
      #pragma unroll
      for (int d = 1; d < 64; d <<= 1) {
        int o = __shfl_down(suf, d);
        if (tid + d < 64) suf += o;
      }
      int above = suf - tot;
      int c3 = h3 + above;
      int c2 = c3 + h2;
      int c1 = c2 + h1;
      int c0 = c1 + h0;
      if      (c3 >= k && above < k) { s_digit = 4*tid+3; s_krem = k - above; s_break = (h3 == 1); }
      else if (c2 >= k && c3    < k) { s_digit = 4*tid+2; s_krem = k - c3;    s_break = (h2 == 1); }
      else if (c1 >= k && c2    < k) { s_digit = 4*tid+1; s_krem = k - c2;    s_break = (h1 == 1); }
      else if (c0 >= k && c1    < k) { s_digit = 4*tid+0; s_krem = k - c1;    s_break = (h0 == 1); }
    }
    __syncthreads();
    prefix |= ((unsigned long long)s_digit) << shift;
    k = s_krem;
    brk = s_break;
  }

  if (shift == 0) {
    if (tid == 0) s_T = prefix;
  } else {
    unsigned long long known_mask = ~0ULL << shift;
    #pragma unroll
    for (int r = 0; r < 16; ++r)
      if ((rk[r] & known_mask) == prefix) s_T = rk[r];
  }
  __syncthreads();
  unsigned long long T = s_T;

  #pragma unroll
  for (int r = 0; r < 16; ++r) {
    unsigned long long kk = rk[r];
    if (kk >= T) { int pos = atomicAdd(&s_cnt, 1); s_sel[pos] = kk; }
  }
  __syncthreads();

  int my_rank = -1, my_v = 0;
  if (tid < NN) {
    unsigned long long mine = s_sel[tid];
    int rank = 0;
    #pragma unroll 16
    for (int j = 0; j < NN; ++j) rank += (s_sel[j] > mine) ? 1 : 0;
    unsigned bits = (unsigned)(mine >> 32);
    int v = bits > 0x3F000000u ? 1 : 0;
    int idx = (int)(0xFFFFFFFFu - (unsigned)(mine & 0xFFFFFFFFull));
    if (v) atomicAdd(&s_vcnt, 1);
    topi[b*NN + rank] = idx;
    valid[b*NN + rank] = v;
    int iy = idx >> 7;
    int ix = idx & 127;
    float yo = off[((size_t)b*2 + 0) * NPIX + idx];
    float xo = off[((size_t)b*2 + 1) * NPIX + idx];
    out_nodes[(b*NN + rank)*2 + 0] = ((float)ix + 0.5f + xo) * 4.0f;
    out_nodes[(b*NN + rank)*2 + 1] = ((float)iy + 0.5f + yo) * 4.0f;
    my_rank = rank; my_v = v;
  }
  __syncthreads();
  if (tid < NN) {
    int V = s_vcnt;
    inv_deg[b*NN + my_rank] = (my_v && V >= 2) ? 1.0f / (float)(V - 1) : 0.0f;
  }
}

// ---------------- Kernel 2: gather node features + fused colsum into S0 ----------------
__global__ __launch_bounds__(256) void k_gather(
    const float* __restrict__ nmap, const int* __restrict__ topi,
    const int* __restrict__ valid, float* __restrict__ x, float* __restrict__ S0)
{
  const int bn = blockIdx.x;
  const int b = bn >> 8;
  const int c = threadIdx.x;
  int pix = topi[bn];
  int v = valid[bn];
  float val = v ? nmap[(((size_t)b*CC + c) << 14) + pix] : 0.0f;
  x[(size_t)bn*CC + c] = val;
  if (val != 0.0f) atomicAdd(&S0[b*CC + c], val);
}

// ---------------- Kernel 3: GNN layer ----------------
// out[r][col] = relu(A1 + inv_r*(P2[col] - A2) + bias) * valid
// A1 = x@Wself, A2 = x@Wnbr, P2 = S@Wnbr (S fused as extra stream).
// Block: 2 rows x 128 col-pairs x K-split 4 = 512 thr. Grid 512 (2 blocks/CU, 16 waves/CU).
// x/S staged in LDS, read as wave-uniform b128 broadcasts (off the L2-latency path).
// Weights as float2 per col-pair: 8 independent L2 loads/c4 -> memory-level parallelism.
__global__ __launch_bounds__(512, 4) void k_gnn(
    const float* __restrict__ x, const float* __restrict__ S,
    const float* __restrict__ inv_deg, const int* __restrict__ valid,
    const float* __restrict__ Wself, const float* __restrict__ Wnbr,
    const float* __restrict__ bias, float* __restrict__ xout,
    float* __restrict__ Snext,     // may be null
    float* __restrict__ out_emb)   // may be null
{
  __shared__ float sx0[CC], sx1[CC], ss[CC];   // 3 KiB
  __shared__ float red[3][10][128];            // 15 KiB
  const int n0  = blockIdx.x * 2;              // global row, 0..1022
  const int b   = n0 >> 8;
  const int tid = threadIdx.x;
  const int cp  = tid & 127;                   // col pair
  const int kw  = tid >> 7;                    // 0..3 K-quarter
  const int col0 = cp << 1;

  if (tid < 256) {
    sx0[tid] = x[(size_t)n0*CC + tid];
    ss[tid]  = S[b*CC + tid];
  } else {
    sx1[tid - 256] = x[(size_t)(n0+1)*CC + (tid - 256)];
  }
  __syncthreads();

  const float4* x0v = (const float4*)sx0;
  const float4* x1v = (const float4*)sx1;
  const float4* ssv = (const float4*)ss;
  const float2* W1v = (const float2*)Wself;    // [(c)*128 + cp]
  const float2* W2v = (const float2*)Wnbr;

  float a1r0c0=0, a1r0c1=0, a1r1c0=0, a1r1c1=0;
  float a2r0c0=0, a2r0c1=0, a2r1c0=0, a2r1c1=0;
  float aSc0=0, aSc1=0;

  #pragma unroll 2
  for (int c4 = 0; c4 < 16; ++c4) {
    int q = (kw << 4) + c4;          // float4 index; c = 4q
    float4 xv0 = x0v[q];
    float4 xv1 = x1v[q];
    float4 sv  = ssv[q];
    size_t wb = (size_t)(q << 2) * 128 + cp;
    float2 w1a = W1v[wb];
    float2 w2a = W2v[wb];
    float2 w1b = W1v[wb + 128];
    float2 w2b = W2v[wb + 128];
    float2 w1c = W1v[wb + 256];
    float2 w2c = W2v[wb + 256];
    float2 w1d = W1v[wb + 384];
    float2 w2d = W2v[wb + 384];
    a1r0c0 += xv0.x*w1a.x; a1r0c1 += xv0.x*w1a.y;
    a1r1c0 += xv1.x*w1a.x; a1r1c1 += xv1.x*w1a.y;
    a2r0c0 += xv0.x*w2a.x; a2r0c1 += xv0.x*w2a.y;
    a2r1c0 += xv1.x*w2a.x; a2r1c1 += xv1.x*w2a.y;
    aSc0   += sv.x *w2a.x; aSc1   += sv.x *w2a.y;
    a1r0c0 += xv0.y*w1b.x; a1r0c1 += xv0.y*w1b.y;
    a1r1c0 += xv1.y*w1b.x; a1r1c1 += xv1.y*w1b.y;
    a2r0c0 += xv0.y*w2b.x; a2r0c1 += xv0.y*w2b.y;
    a2r1c0 += xv1.y*w2b.x; a2r1c1 += xv1.y*w2b.y;
    aSc0   += sv.y *w2b.x; aSc1   += sv.y *w2b.y;
    a1r0c0 += xv0.z*w1c.x; a1r0c1 += xv0.z*w1c.y;
    a1r1c0 += xv1.z*w1c.x; a1r1c1 += xv1.z*w1c.y;
    a2r0c0 += xv0.z*w2c.x; a2r0c1 += xv0.z*w2c.y;
    a2r1c0 += xv1.z*w2c.x; a2r1c1 += xv1.z*w2c.y;
    aSc0   += sv.z *w2c.x; aSc1   += sv.z *w2c.y;
    a1r0c0 += xv0.w*w1d.x; a1r0c1 += xv0.w*w1d.y;
    a1r1c0 += xv1.w*w1d.x; a1r1c1 += xv1.w*w1d.y;
    a2r0c0 += xv0.w*w2d.x; a2r0c1 += xv0.w*w2d.y;
    a2r1c0 += xv1.w*w2d.x; a2r1c1 += xv1.w*w2d.y;
    aSc0   += sv.w *w2d.x; aSc1   += sv.w *w2d.y;
  }

  if (kw > 0) {
    red[kw-1][0][cp]=a1r0c0; red[kw-1][1][cp]=a1r0c1;
    red[kw-1][2][cp]=a1r1c0; red[kw-1][3][cp]=a1r1c1;
    red[kw-1][4][cp]=a2r0c0; red[kw-1][5][cp]=a2r0c1;
    red[kw-1][6][cp]=a2r1c0; red[kw-1][7][cp]=a2r1c1;
    red[kw-1][8][cp]=aSc0;   red[kw-1][9][cp]=aSc1;
  }
  __syncthreads();
  if (kw == 0) {
    #pragma unroll
    for (int g = 0; g < 3; ++g) {
      a1r0c0 += red[g][0][cp]; a1r0c1 += red[g][1][cp];
      a1r1c0 += red[g][2][cp]; a1r1c1 += red[g][3][cp];
      a2r0c0 += red[g][4][cp]; a2r0c1 += red[g][5][cp];
      a2r1c0 += red[g][6][cp]; a2r1c1 += red[g][7][cp];
      aSc0   += red[g][8][cp]; aSc1   += red[g][9][cp];
    }
    float bv0 = bias[col0], bv1 = bias[col0+1];
    int   va0 = valid[n0],  va1 = valid[n0+1];
    float in0 = inv_deg[n0], in1 = inv_deg[n0+1];
    float o00 = fmaxf(a1r0c0 + in0*(aSc0 - a2r0c0) + bv0, 0.f); o00 = va0 ? o00 : 0.f;
    float o01 = fmaxf(a1r0c1 + in0*(aSc1 - a2r0c1) + bv1, 0.f); o01 = va0 ? o01 : 0.f;
    float o10 = fmaxf(a1r1c0 + in1*(aSc0 - a2r1c0) + bv0, 0.f); o10 = va1 ? o10 : 0.f;
    float o11 = fmaxf(a1r1c1 + in1*(aSc1 - a2r1c1) + bv1, 0.f); o11 = va1 ? o11 : 0.f;
    float2* p0 = (float2*)&xout[(size_t)n0*CC + col0];
    float2* p1 = (float2*)&xout[(size_t)(n0+1)*CC + col0];
    float2 v0; v0.x = o00; v0.y = o01;
    float2 v1; v1.x = o10; v1.y = o11;
    *p0 = v0; *p1 = v1;
    if (out_emb) {
      *(float2*)&out_emb[(size_t)n0*CC + col0]     = v0;
      *(float2*)&out_emb[(size_t)(n0+1)*CC + col0] = v1;
    }
    if (Snext) {
      float cs0 = o00 + o10, cs1 = o01 + o11;
      if (cs0 != 0.f) atomicAdd(&Snext[b*CC + col0],     cs0);
      if (cs1 != 0.f) atomicAdd(&Snext[b*CC + col0 + 1], cs1);
    }
  }
}

// ---------------- Kernel 4: u = x@Ws1[:C], v_t = (x@Ws1[C:])^T ----------------
__global__ __launch_bounds__(512) void k_uv(
    const float* __restrict__ x, const float* __restrict__ Ws1,
    float* __restrict__ u, float* __restrict__ vt)
{
  __shared__ float red[3][8][128];   // 12 KiB
  const int b   = blockIdx.x >> 6;
  const int n0  = (blockIdx.x & 63) * 4;
  const int tid = threadIdx.x;
  const int h   = tid & 127;
  const int kw  = tid >> 7;          // 0..3, 64 c's each

  const float4* x4 = (const float4*)(x + ((size_t)(b*NN + n0))*CC);
  float au0=0,au1=0,au2=0,au3=0, av0=0,av1=0,av2=0,av3=0;
  #pragma unroll 2
  for (int c4 = 0; c4 < 16; ++c4) {
    int q = kw*16 + c4;
    float4 xv0 = x4[q];
    float4 xv1 = x4[64 + q];
    float4 xv2 = x4[128 + q];
    float4 xv3 = x4[192 + q];
    int cb = q << 2;
    {
      float w1 = Ws1[(size_t)(cb+0)*HH + h];
      float w2 = Ws1[(size_t)(256+cb+0)*HH + h];
      au0 += xv0.x*w1; av0 += xv0.x*w2;
      au1 += xv1.x*w1; av1 += xv1.x*w2;
      au2 += xv2.x*w1; av2 += xv2.x*w2;
      au3 += xv3.x*w1; av3 += xv3.x*w2;
    }
    {
      float w1 = Ws1[(size_t)(cb+1)*HH + h];
      float w2 = Ws1[(size_t)(256+cb+1)*HH + h];
      au0 += xv0.y*w1; av0 += xv0.y*w2;
      au1 += xv1.y*w1; av1 += xv1.y*w2;
      au2 += xv2.y*w1; av2 += xv2.y*w2;
      au3 += xv3.y*w1; av3 += xv3.y*w2;
    }
    {
      float w1 = Ws1[(size_t)(cb+2)*HH + h];
      float w2 = Ws1[(size_t)(256+cb+2)*HH + h];
      au0 += xv0.z*w1; av0 += xv0.z*w2;
      au1 += xv1.z*w1; av1 += xv1.z*w2;
      au2 += xv2.z*w1; av2 += xv2.z*w2;
      au3 += xv3.z*w1; av3 += xv3.z*w2;
    }
    {
      float w1 = Ws1[(size_t)(cb+3)*HH + h];
      float w2 = Ws1[(size_t)(256+cb+3)*HH + h];
      au0 += xv0.w*w1; av0 += xv0.w*w2;
      au1 += xv1.w*w1; av1 += xv1.w*w2;
      au2 += xv2.w*w1; av2 += xv2.w*w2;
      au3 += xv3.w*w1; av3 += xv3.w*w2;
    }
  }
  if (kw > 0) {
    red[kw-1][0][h]=au0; red[kw-1][1][h]=au1; red[kw-1][2][h]=au2; red[kw-1][3][h]=au3;
    red[kw-1][4][h]=av0; red[kw-1][5][h]=av1; red[kw-1][6][h]=av2; red[kw-1][7][h]=av3;
  }
  __syncthreads();
  if (kw == 0) {
    float AU[4] = {au0,au1,au2,au3};
    float AV[4] = {av0,av1,av2,av3};
    #pragma unroll
    for (int g = 0; g < 3; ++g) {
      AU[0] += red[g][0][h]; AU[1] += red[g][1][h];
      AU[2] += red[g][2][h]; AU[3] += red[g][3][h];
      AV[0] += red[g][4][h]; AV[1] += red[g][5][h];
      AV[2] += red[g][6][h]; AV[3] += red[g][7][h];
    }
    #pragma unroll
    for (int r = 0; r < 4; ++r) {
      u [((size_t)(b*NN + n0 + r))*HH + h] = AU[r];
      vt[((size_t)b*HH + h)*NN + (n0 + r)] = AV[r];
    }
  }
}

// ---------------- Kernel 5: per-edge scorer, LDS-free ----------------
__global__ __launch_bounds__(256) void k_edges(
    const float* __restrict__ u, const float* __restrict__ vt,
    const float* __restrict__ bs1, const float* __restrict__ Ws2,
    const float* __restrict__ bs2, const int* __restrict__ valid,
    float* __restrict__ out_logits, float* __restrict__ out_keep)
{
  const int b = blockIdx.x >> 8;
  const int i = blockIdx.x & 255;   // src node
  const int j = threadIdx.x;        // dst node
  const float4* u4  = (const float4*)(u + ((size_t)(b*NN + i))*HH);
  const float4* b14 = (const float4*)bs1;
  const float4* w24 = (const float4*)Ws2;
  const float* vrow = vt + (size_t)b*HH*NN;
  float acc = 0.f;
  #pragma unroll 4
  for (int h4 = 0; h4 < 32; ++h4) {
    float4 uu = u4[h4];
    float4 bb = b14[h4];
    float4 ww = w24[h4];
    int hb = h4 << 2;
    float t0 = uu.x + bb.x + vrow[(size_t)(hb+0)*NN + j];
    float t1 = uu.y + bb.y + vrow[(size_t)(hb+1)*NN + j];
    float t2 = uu.z + bb.z + vrow[(size_t)(hb+2)*NN + j];
    float t3 = uu.w + bb.w + vrow[(size_t)(hb+3)*NN + j];
    acc += fmaxf(t0, 0.f)*ww.x + fmaxf(t1, 0.f)*ww.y
         + fmaxf(t2, 0.f)*ww.z + fmaxf(t3, 0.f)*ww.w;
  }
  acc += bs2[0];
  if (j != i) {
    int e = i*255 + (j < i ? j : j - 1);
    int ev = valid[b*NN + i] & valid[b*NN + j];
    out_logits[(size_t)b*EE + e] = acc;
    out_keep  [(size_t)b*EE + e] = (acc > 0.f && ev) ? 1.0f : 0.0f;
  }
}

extern "C" void kernel_launch(void* const* d_in, const int* in_sizes, int n_in,
                              void* d_out, int out_size, void* d_ws, size_t ws_size,
                              hipStream_t stream) {
  const float* jl    = (const float*)d_in[0];
  const float* off   = (const float*)d_in[1];
  const float* nmap  = (const float*)d_in[2];
  const float* Wself = (const float*)d_in[3];
  const float* Wnbr  = (const float*)d_in[4];
  const float* bg    = (const float*)d_in[5];
  const float* Ws1   = (const float*)d_in[6];
  const float* bs1   = (const float*)d_in[7];
  const float* Ws2   = (const float*)d_in[8];
  const float* bs2   = (const float*)d_in[9];

  char* ws = (char*)d_ws;
  int*   topi    = (int*)  (ws + 0);                 //  4 KiB
  int*   valid   = (int*)  (ws + 4096);              //  4 KiB
  float* inv_deg = (float*)(ws + 8192);              //  4 KiB
  float* Sbuf    = (float*)(ws + 12288);             // 16 KiB (layer colsums)
  float* xa      = (float*)(ws + 28672);             //  1 MiB
  float* xb      = (float*)(ws + 28672 + 1048576);   //  1 MiB
  float* u       = (float*)(ws + 2125824);           //  512 KiB
  float* vt      = (float*)(ws + 2650112);           //  512 KiB

  float* out        = (float*)d_out;
  float* out_nodes  = out;                  // [4,256,2]   -> 2048
  float* out_emb    = out + 2048;           // [4,256,256] -> 262144
  float* out_logits = out + 264192;         // [4,65280]   -> 261120
  float* out_keep   = out + 525312;         // [4,65280]   -> 261120

  hipLaunchKernelGGL(k_topk,   dim3(BB),     dim3(1024), 0, stream,
                     jl, off, topi, valid, inv_deg, out_nodes, Sbuf);
  hipLaunchKernelGGL(k_gather, dim3(BB*NN),  dim3(256),  0, stream,
                     nmap, topi, valid, xa, Sbuf);

  float* xc = xa; float* xn = xb;
  for (int l = 0; l < 3; ++l) {
    hipLaunchKernelGGL(k_gnn, dim3(512), dim3(512), 0, stream,
                       xc, Sbuf + l*BB*CC, inv_deg, valid,
                       Wself + (size_t)l*CC*CC, Wnbr + (size_t)l*CC*CC, bg + l*CC,
                       xn,
                       (l < 2) ? (Sbuf + (l+1)*BB*CC) : (float*)nullptr,
                       (l == 2) ? out_emb : (float*)nullptr);
    float* t = xc; xc = xn; xn = t;
  }

  hipLaunchKernelGGL(k_uv,    dim3(256),   dim3(512), 0, stream, xc, Ws1, u, vt);
  hipLaunchKernelGGL(k_edges, dim3(BB*NN), dim3(256), 0, stream,
                     u, vt, bs1, Ws2, bs2, valid, out_logits, out_keep);
}

// Round 10
// 98.007 us; speedup vs baseline: 1.3911x; 1.2275x over previous
//
#include <hip/hip_runtime.h>

#define NPIX 16384   // 128*128
#define NN   256     // max_nodes
#define CC   256     // NFEAT
#define HH   128     // SCORER_HIDDEN
#define EE   65280   // NN*(NN-1)
#define BB   4
#define NG   8       // histogram privatization groups
#define NWELEM 196608        // 3*256*256 per weight tensor
#define CONV_BLOCKS 384      // 2*NWELEM / 1024

// ---------------- Kernel 1: top-k (blocks 0..3) + weight bf16 convert (blocks 4..387) ----
// Convert rides on idle CUs while the 4 sort blocks run; warms L3 with the weight
// stream and emits bf16 copies (halves the per-layer cold HBM fetch in k_gnn).
__global__ __launch_bounds__(1024) void k_topk(
    const float* __restrict__ jl, const float* __restrict__ off,
    int* __restrict__ topi, int* __restrict__ valid, float* __restrict__ inv_deg,
    float* __restrict__ out_nodes, float* __restrict__ Sbuf,
    const float* __restrict__ Wself_f, const float* __restrict__ Wnbr_f,
    unsigned short* __restrict__ wbf)   // [2*NWELEM]: Wself then Wnbr
{
  __shared__ int hist[NG][257];
  __shared__ int histT[256];
  __shared__ unsigned long long s_sel[NN];
  __shared__ unsigned long long s_T;
  __shared__ int s_digit, s_krem, s_cnt, s_vcnt, s_break;

  const int bid = blockIdx.x;
  const int tid = threadIdx.x;

  if (bid >= BB) {
    // ---- bf16 weight conversion (round-to-nearest-even) ----
    int i = (bid - BB) * 1024 + tid;        // 0 .. 2*NWELEM-1 exactly
    float v = (i < NWELEM) ? Wself_f[i] : Wnbr_f[i - NWELEM];
    unsigned b = __float_as_uint(v);
    unsigned r = (b + 0x7fffu + ((b >> 16) & 1u)) >> 16;
    wbf[i] = (unsigned short)r;
    return;
  }

  const int b = bid;
  const int grp = (tid >> 7) & (NG - 1);
  if (tid == 0) { s_cnt = 0; s_vcnt = 0; }

  // zero the 4 colsum buffers for this image (layout: Sbuf[l*BB*CC + b*CC + c])
  {
    int l = tid >> 8, c = tid & 255;
    Sbuf[l*BB*CC + b*CC + c] = 0.0f;
  }

  unsigned long long rk[16];
  const float* p = jl + (size_t)b * NPIX;
  #pragma unroll
  for (int r = 0; r < 16; ++r) {
    int i = tid + (r << 10);
    float x = p[i];
    float pr = 1.0f / (1.0f + expf(-x));
    unsigned bits = __float_as_uint(pr);
    rk[r] = ((unsigned long long)bits << 32) | (unsigned)(0xFFFFFFFFu - (unsigned)i);
  }

  unsigned long long prefix = 0;
  int k = NN;
  int shift = 56;
  int brk = 0;
  for (int pass = 0; pass < 8 && !brk; ++pass) {
    shift = 56 - 8 * pass;
    for (int i = tid; i < NG * 257; i += 1024) ((int*)hist)[i] = 0;
    __syncthreads();
    unsigned long long pmask = (pass == 0) ? 0ULL : (~0ULL << (shift + 8));
    #pragma unroll
    for (int r = 0; r < 16; ++r) {
      unsigned long long kk = rk[r];
      if ((kk & pmask) == prefix)
        atomicAdd(&hist[grp][(int)((kk >> shift) & 255)], 1);
    }
    __syncthreads();
    if (tid < 256) {
      int t = 0;
      #pragma unroll
      for (int g = 0; g < NG; ++g) t += hist[g][tid];
      histT[tid] = t;
    }
    __syncthreads();
    if (tid < 64) {
      int h0 = histT[4*tid + 0], h1 = histT[4*tid + 1];
      int h2 = histT[4*tid + 2], h3 = histT[4*tid + 3];
      int tot = h0 + h1 + h2 + h3;
      int suf = tot;
      #pragma unroll
      for (int d = 1; d < 64; d <<= 1) {
        int o = __shfl_down(suf, d);
        if (tid + d < 64) suf += o;
      }
      int above = suf - tot;
      int c3 = h3 + above;
      int c2 = c3 + h2;
      int c1 = c2 + h1;
      int c0 = c1 + h0;
      if      (c3 >= k && above < k) { s_digit = 4*tid+3; s_krem = k - above; s_break = (h3 == 1); }
      else if (c2 >= k && c3    < k) { s_digit = 4*tid+2; s_krem = k - c3;    s_break = (h2 == 1); }
      else if (c1 >= k && c2    < k) { s_digit = 4*tid+1; s_krem = k - c2;    s_break = (h1 == 1); }
      else if (c0 >= k && c1    < k) { s_digit = 4*tid+0; s_krem = k - c1;    s_break = (h0 == 1); }
    }
    __syncthreads();
    prefix |= ((unsigned long long)s_digit) << shift;
    k = s_krem;
    brk = s_break;
  }

  if (shift == 0) {
    if (tid == 0) s_T = prefix;
  } else {
    unsigned long long known_mask = ~0ULL << shift;
    #pragma unroll
    for (int r = 0; r < 16; ++r)
      if ((rk[r] & known_mask) == prefix) s_T = rk[r];
  }
  __syncthreads();
  unsigned long long T = s_T;

  #pragma unroll
  for (int r = 0; r < 16; ++r) {
    unsigned long long kk = rk[r];
    if (kk >= T) { int pos = atomicAdd(&s_cnt, 1); s_sel[pos] = kk; }
  }
  __syncthreads();

  int my_rank = -1, my_v = 0;
  if (tid < NN) {
    unsigned long long mine = s_sel[tid];
    int rank = 0;
    #pragma unroll 16
    for (int j = 0; j < NN; ++j) rank += (s_sel[j] > mine) ? 1 : 0;
    unsigned bits = (unsigned)(mine >> 32);
    int v = bits > 0x3F000000u ? 1 : 0;
    int idx = (int)(0xFFFFFFFFu - (unsigned)(mine & 0xFFFFFFFFull));
    if (v) atomicAdd(&s_vcnt, 1);
    topi[b*NN + rank] = idx;
    valid[b*NN + rank] = v;
    int iy = idx >> 7;
    int ix = idx & 127;
    float yo = off[((size_t)b*2 + 0) * NPIX + idx];
    float xo = off[((size_t)b*2 + 1) * NPIX + idx];
    out_nodes[(b*NN + rank)*2 + 0] = ((float)ix + 0.5f + xo) * 4.0f;
    out_nodes[(b*NN + rank)*2 + 1] = ((float)iy + 0.5f + yo) * 4.0f;
    my_rank = rank; my_v = v;
  }
  __syncthreads();
  if (tid < NN) {
    int V = s_vcnt;
    inv_deg[b*NN + my_rank] = (my_v && V >= 2) ? 1.0f / (float)(V - 1) : 0.0f;
  }
}

// ---------------- Kernel 2: gather node features + fused colsum into S0 ----------------
__global__ __launch_bounds__(256) void k_gather(
    const float* __restrict__ nmap, const int* __restrict__ topi,
    const int* __restrict__ valid, float* __restrict__ x, float* __restrict__ S0)
{
  const int bn = blockIdx.x;
  const int b = bn >> 8;
  const int c = threadIdx.x;
  int pix = topi[bn];
  int v = valid[bn];
  float val = v ? nmap[(((size_t)b*CC + c) << 14) + pix] : 0.0f;
  x[(size_t)bn*CC + c] = val;
  if (val != 0.0f) atomicAdd(&S0[b*CC + c], val);
}

// ---------------- Kernel 3: GNN layer, bf16 weights (uint = col-pair) ----------------
// out[r][col] = relu(A1 + inv_r*(P2[col] - A2) + bias) * valid
// A1 = x@Wself, A2 = x@Wnbr, P2 = S@Wnbr (S fused as extra stream).
// Block: 2 rows x 128 col-pairs x K-split 4 = 512 thr. Grid 512 (16 waves/CU).
// Weights bf16: one uint load = both cols' weight; fp32 x/accumulate.
__global__ __launch_bounds__(512, 4) void k_gnn(
    const float* __restrict__ x, const float* __restrict__ S,
    const float* __restrict__ inv_deg, const int* __restrict__ valid,
    const unsigned short* __restrict__ Wself, const unsigned short* __restrict__ Wnbr,
    const float* __restrict__ bias, float* __restrict__ xout,
    float* __restrict__ Snext,     // may be null
    float* __restrict__ out_emb)   // may be null
{
  __shared__ float sx0[CC], sx1[CC], ss[CC];   // 3 KiB
  __shared__ float red[3][10][128];            // 15 KiB
  const int n0  = blockIdx.x * 2;              // global row, 0..1022
  const int b   = n0 >> 8;
  const int tid = threadIdx.x;
  const int cp  = tid & 127;                   // col pair
  const int kw  = tid >> 7;                    // 0..3 K-quarter
  const int col0 = cp << 1;

  if (tid < 256) {
    sx0[tid] = x[(size_t)n0*CC + tid];
    ss[tid]  = S[b*CC + tid];
  } else {
    sx1[tid - 256] = x[(size_t)(n0+1)*CC + (tid - 256)];
  }
  __syncthreads();

  const float4* x0v = (const float4*)sx0;
  const float4* x1v = (const float4*)sx1;
  const float4* ssv = (const float4*)ss;
  const unsigned* W1u = (const unsigned*)Wself;   // [c*128 + cp] -> cols (2cp, 2cp+1)
  const unsigned* W2u = (const unsigned*)Wnbr;

  float a1r0c0=0, a1r0c1=0, a1r1c0=0, a1r1c1=0;
  float a2r0c0=0, a2r0c1=0, a2r1c0=0, a2r1c1=0;
  float aSc0=0, aSc1=0;

  #pragma unroll 4
  for (int c4 = 0; c4 < 16; ++c4) {
    int q = (kw << 4) + c4;          // float4 index; c = 4q
    float4 xv0 = x0v[q];
    float4 xv1 = x1v[q];
    float4 sv  = ssv[q];
    int wb = (q << 2) * 128 + cp;
    unsigned u1a = W1u[wb];       unsigned u2a = W2u[wb];
    unsigned u1b = W1u[wb + 128]; unsigned u2b = W2u[wb + 128];
    unsigned u1c = W1u[wb + 256]; unsigned u2c = W2u[wb + 256];
    unsigned u1d = W1u[wb + 384]; unsigned u2d = W2u[wb + 384];

    float w1a0 = __uint_as_float(u1a << 16), w1a1 = __uint_as_float(u1a & 0xFFFF0000u);
    float w2a0 = __uint_as_float(u2a << 16), w2a1 = __uint_as_float(u2a & 0xFFFF0000u);
    a1r0c0 += xv0.x*w1a0; a1r0c1 += xv0.x*w1a1;
    a1r1c0 += xv1.x*w1a0; a1r1c1 += xv1.x*w1a1;
    a2r0c0 += xv0.x*w2a0; a2r0c1 += xv0.x*w2a1;
    a2r1c0 += xv1.x*w2a0; a2r1c1 += xv1.x*w2a1;
    aSc0   += sv.x *w2a0; aSc1   += sv.x *w2a1;

    float w1b0 = __uint_as_float(u1b << 16), w1b1 = __uint_as_float(u1b & 0xFFFF0000u);
    float w2b0 = __uint_as_float(u2b << 16), w2b1 = __uint_as_float(u2b & 0xFFFF0000u);
    a1r0c0 += xv0.y*w1b0; a1r0c1 += xv0.y*w1b1;
    a1r1c0 += xv1.y*w1b0; a1r1c1 += xv1.y*w1b1;
    a2r0c0 += xv0.y*w2b0; a2r0c1 += xv0.y*w2b1;
    a2r1c0 += xv1.y*w2b0; a2r1c1 += xv1.y*w2b1;
    aSc0   += sv.y *w2b0; aSc1   += sv.y *w2b1;

    float w1c0 = __uint_as_float(u1c << 16), w1c1 = __uint_as_float(u1c & 0xFFFF0000u);
    float w2c0 = __uint_as_float(u2c << 16), w2c1 = __uint_as_float(u2c & 0xFFFF0000u);
    a1r0c0 += xv0.z*w1c0; a1r0c1 += xv0.z*w1c1;
    a1r1c0 += xv1.z*w1c0; a1r1c1 += xv1.z*w1c1;
    a2r0c0 += xv0.z*w2c0; a2r0c1 += xv0.z*w2c1;
    a2r1c0 += xv1.z*w2c0; a2r1c1 += xv1.z*w2c1;
    aSc0   += sv.z *w2c0; aSc1   += sv.z *w2c1;

    float w1d0 = __uint_as_float(u1d << 16), w1d1 = __uint_as_float(u1d & 0xFFFF0000u);
    float w2d0 = __uint_as_float(u2d << 16), w2d1 = __uint_as_float(u2d & 0xFFFF0000u);
    a1r0c0 += xv0.w*w1d0; a1r0c1 += xv0.w*w1d1;
    a1r1c0 += xv1.w*w1d0; a1r1c1 += xv1.w*w1d1;
    a2r0c0 += xv0.w*w2d0; a2r0c1 += xv0.w*w2d1;
    a2r1c0 += xv1.w*w2d0; a2r1c1 += xv1.w*w2d1;
    aSc0   += sv.w *w2d0; aSc1   += sv.w *w2d1;
  }

  if (kw > 0) {
    red[kw-1][0][cp]=a1r0c0; red[kw-1][1][cp]=a1r0c1;
    red[kw-1][2][cp]=a1r1c0; red[kw-1][3][cp]=a1r1c1;
    red[kw-1][4][cp]=a2r0c0; red[kw-1][5][cp]=a2r0c1;
    red[kw-1][6][cp]=a2r1c0; red[kw-1][7][cp]=a2r1c1;
    red[kw-1][8][cp]=aSc0;   red[kw-1][9][cp]=aSc1;
  }
  __syncthreads();
  if (kw == 0) {
    #pragma unroll
    for (int g = 0; g < 3; ++g) {
      a1r0c0 += red[g][0][cp]; a1r0c1 += red[g][1][cp];
      a1r1c0 += red[g][2][cp]; a1r1c1 += red[g][3][cp];
      a2r0c0 += red[g][4][cp]; a2r0c1 += red[g][5][cp];
      a2r1c0 += red[g][6][cp]; a2r1c1 += red[g][7][cp];
      aSc0   += red[g][8][cp]; aSc1   += red[g][9][cp];
    }
    float bv0 = bias[col0], bv1 = bias[col0+1];
    int   va0 = valid[n0],  va1 = valid[n0+1];
    float in0 = inv_deg[n0], in1 = inv_deg[n0+1];
    float o00 = fmaxf(a1r0c0 + in0*(aSc0 - a2r0c0) + bv0, 0.f); o00 = va0 ? o00 : 0.f;
    float o01 = fmaxf(a1r0c1 + in0*(aSc1 - a2r0c1) + bv1, 0.f); o01 = va0 ? o01 : 0.f;
    float o10 = fmaxf(a1r1c0 + in1*(aSc0 - a2r1c0) + bv0, 0.f); o10 = va1 ? o10 : 0.f;
    float o11 = fmaxf(a1r1c1 + in1*(aSc1 - a2r1c1) + bv1, 0.f); o11 = va1 ? o11 : 0.f;
    float2* p0 = (float2*)&xout[(size_t)n0*CC + col0];
    float2* p1 = (float2*)&xout[(size_t)(n0+1)*CC + col0];
    float2 v0; v0.x = o00; v0.y = o01;
    float2 v1; v1.x = o10; v1.y = o11;
    *p0 = v0; *p1 = v1;
    if (out_emb) {
      *(float2*)&out_emb[(size_t)n0*CC + col0]     = v0;
      *(float2*)&out_emb[(size_t)(n0+1)*CC + col0] = v1;
    }
    if (Snext) {
      float cs0 = o00 + o10, cs1 = o01 + o11;
      if (cs0 != 0.f) atomicAdd(&Snext[b*CC + col0],     cs0);
      if (cs1 != 0.f) atomicAdd(&Snext[b*CC + col0 + 1], cs1);
    }
  }
}

// ---------------- Kernel 4: u = x@Ws1[:C], v_t = (x@Ws1[C:])^T ----------------
__global__ __launch_bounds__(512) void k_uv(
    const float* __restrict__ x, const float* __restrict__ Ws1,
    float* __restrict__ u, float* __restrict__ vt)
{
  __shared__ float red[3][8][128];   // 12 KiB
  const int b   = blockIdx.x >> 6;
  const int n0  = (blockIdx.x & 63) * 4;
  const int tid = threadIdx.x;
  const int h   = tid & 127;
  const int kw  = tid >> 7;          // 0..3, 64 c's each

  const float4* x4 = (const float4*)(x + ((size_t)(b*NN + n0))*CC);
  float au0=0,au1=0,au2=0,au3=0, av0=0,av1=0,av2=0,av3=0;
  #pragma unroll 2
  for (int c4 = 0; c4 < 16; ++c4) {
    int q = kw*16 + c4;
    float4 xv0 = x4[q];
    float4 xv1 = x4[64 + q];
    float4 xv2 = x4[128 + q];
    float4 xv3 = x4[192 + q];
    int cb = q << 2;
    {
      float w1 = Ws1[(size_t)(cb+0)*HH + h];
      float w2 = Ws1[(size_t)(256+cb+0)*HH + h];
      au0 += xv0.x*w1; av0 += xv0.x*w2;
      au1 += xv1.x*w1; av1 += xv1.x*w2;
      au2 += xv2.x*w1; av2 += xv2.x*w2;
      au3 += xv3.x*w1; av3 += xv3.x*w2;
    }
    {
      float w1 = Ws1[(size_t)(cb+1)*HH + h];
      float w2 = Ws1[(size_t)(256+cb+1)*HH + h];
      au0 += xv0.y*w1; av0 += xv0.y*w2;
      au1 += xv1.y*w1; av1 += xv1.y*w2;
      au2 += xv2.y*w1; av2 += xv2.y*w2;
      au3 += xv3.y*w1; av3 += xv3.y*w2;
    }
    {
      float w1 = Ws1[(size_t)(cb+2)*HH + h];
      float w2 = Ws1[(size_t)(256+cb+2)*HH + h];
      au0 += xv0.z*w1; av0 += xv0.z*w2;
      au1 += xv1.z*w1; av1 += xv1.z*w2;
      au2 += xv2.z*w1; av2 += xv2.z*w2;
      au3 += xv3.z*w1; av3 += xv3.z*w2;
    }
    {
      float w1 = Ws1[(size_t)(cb+3)*HH + h];
      float w2 = Ws1[(size_t)(256+cb+3)*HH + h];
      au0 += xv0.w*w1; av0 += xv0.w*w2;
      au1 += xv1.w*w1; av1 += xv1.w*w2;
      au2 += xv2.w*w1; av2 += xv2.w*w2;
      au3 += xv3.w*w1; av3 += xv3.w*w2;
    }
  }
  if (kw > 0) {
    red[kw-1][0][h]=au0; red[kw-1][1][h]=au1; red[kw-1][2][h]=au2; red[kw-1][3][h]=au3;
    red[kw-1][4][h]=av0; red[kw-1][5][h]=av1; red[kw-1][6][h]=av2; red[kw-1][7][h]=av3;
  }
  __syncthreads();
  if (kw == 0) {
    float AU[4] = {au0,au1,au2,au3};
    float AV[4] = {av0,av1,av2,av3};
    #pragma unroll
    for (int g = 0; g < 3; ++g) {
      AU[0] += red[g][0][h]; AU[1] += red[g][1][h];
      AU[2] += red[g][2][h]; AU[3] += red[g][3][h];
      AV[0] += red[g][4][h]; AV[1] += red[g][5][h];
      AV[2] += red[g][6][h]; AV[3] += red[g][7][h];
    }
    #pragma unroll
    for (int r = 0; r < 4; ++r) {
      u [((size_t)(b*NN + n0 + r))*HH + h] = AU[r];
      vt[((size_t)b*HH + h)*NN + (n0 + r)] = AV[r];
    }
  }
}

// ---------------- Kernel 5: per-edge scorer, LDS-free ----------------
__global__ __launch_bounds__(256) void k_edges(
    const float* __restrict__ u, const float* __restrict__ vt,
    const float* __restrict__ bs1, const float* __restrict__ Ws2,
    const float* __restrict__ bs2, const int* __restrict__ valid,
    float* __restrict__ out_logits, float* __restrict__ out_keep)
{
  const int b = blockIdx.x >> 8;
  const int i = blockIdx.x & 255;   // src node
  const int j = threadIdx.x;        // dst node
  const float4* u4  = (const float4*)(u + ((size_t)(b*NN + i))*HH);
  const float4* b14 = (const float4*)bs1;
  const float4* w24 = (const float4*)Ws2;
  const float* vrow = vt + (size_t)b*HH*NN;
  float acc = 0.f;
  #pragma unroll 4
  for (int h4 = 0; h4 < 32; ++h4) {
    float4 uu = u4[h4];
    float4 bb = b14[h4];
    float4 ww = w24[h4];
    int hb = h4 << 2;
    float t0 = uu.x + bb.x + vrow[(size_t)(hb+0)*NN + j];
    float t1 = uu.y + bb.y + vrow[(size_t)(hb+1)*NN + j];
    float t2 = uu.z + bb.z + vrow[(size_t)(hb+2)*NN + j];
    float t3 = uu.w + bb.w + vrow[(size_t)(hb+3)*NN + j];
    acc += fmaxf(t0, 0.f)*ww.x + fmaxf(t1, 0.f)*ww.y
         + fmaxf(t2, 0.f)*ww.z + fmaxf(t3, 0.f)*ww.w;
  }
  acc += bs2[0];
  if (j != i) {
    int e = i*255 + (j < i ? j : j - 1);
    int ev = valid[b*NN + i] & valid[b*NN + j];
    out_logits[(size_t)b*EE + e] = acc;
    out_keep  [(size_t)b*EE + e] = (acc > 0.f && ev) ? 1.0f : 0.0f;
  }
}

extern "C" void kernel_launch(void* const* d_in, const int* in_sizes, int n_in,
                              void* d_out, int out_size, void* d_ws, size_t ws_size,
                              hipStream_t stream) {
  const float* jl    = (const float*)d_in[0];
  const float* off   = (const float*)d_in[1];
  const float* nmap  = (const float*)d_in[2];
  const float* Wself = (const float*)d_in[3];
  const float* Wnbr  = (const float*)d_in[4];
  const float* bg    = (const float*)d_in[5];
  const float* Ws1   = (const float*)d_in[6];
  const float* bs1   = (const float*)d_in[7];
  const float* Ws2   = (const float*)d_in[8];
  const float* bs2   = (const float*)d_in[9];

  char* ws = (char*)d_ws;
  int*   topi    = (int*)  (ws + 0);                 //  4 KiB
  int*   valid   = (int*)  (ws + 4096);              //  4 KiB
  float* inv_deg = (float*)(ws + 8192);              //  4 KiB
  float* Sbuf    = (float*)(ws + 12288);             // 16 KiB (layer colsums)
  float* xa      = (float*)(ws + 28672);             //  1 MiB
  float* xb      = (float*)(ws + 28672 + 1048576);   //  1 MiB
  float* u       = (float*)(ws + 2125824);           //  512 KiB
  float* vt      = (float*)(ws + 2650112);           //  512 KiB
  unsigned short* wbf = (unsigned short*)(ws + 3174400);  // 768 KiB bf16 weights

  float* out        = (float*)d_out;
  float* out_nodes  = out;                  // [4,256,2]   -> 2048
  float* out_emb    = out + 2048;           // [4,256,256] -> 262144
  float* out_logits = out + 264192;         // [4,65280]   -> 261120
  float* out_keep   = out + 525312;         // [4,65280]   -> 261120

  unsigned short* wbf_self = wbf;
  unsigned short* wbf_nbr  = wbf + NWELEM;

  hipLaunchKernelGGL(k_topk,   dim3(BB + CONV_BLOCKS), dim3(1024), 0, stream,
                     jl, off, topi, valid, inv_deg, out_nodes, Sbuf,
                     Wself, Wnbr, wbf);
  hipLaunchKernelGGL(k_gather, dim3(BB*NN),  dim3(256),  0, stream,
                     nmap, topi, valid, xa, Sbuf);

  float* xc = xa; float* xn = xb;
  for (int l = 0; l < 3; ++l) {
    hipLaunchKernelGGL(k_gnn, dim3(512), dim3(512), 0, stream,
                       xc, Sbuf + l*BB*CC, inv_deg, valid,
                       wbf_self + (size_t)l*CC*CC, wbf_nbr + (size_t)l*CC*CC, bg + l*CC,
                       xn,
                       (l < 2) ? (Sbuf + (l+1)*BB*CC) : (float*)nullptr,
                       (l == 2) ? out_emb : (float*)nullptr);
    float* t = xc; xc = xn; xn = t;
  }

  hipLaunchKernelGGL(k_uv,    dim3(256),   dim3(512), 0, stream, xc, Ws1, u, vt);
  hipLaunchKernelGGL(k_edges, dim3(BB*NN), dim3(256), 0, stream,
                     u, vt, bs1, Ws2, bs2, valid, out_logits, out_keep);
}